// Round 2
// baseline (1020.762 us; speedup 1.0000x reference)
//
#include <hip/hip_runtime.h>
#include <math.h>

#define IFZ 256
#define KZ  16
#define AHZ 8
#define AFZ 32
#define HF  256   // AHZ*AFZ

// ---------------------------------------------------------------------------
// GEMM: Y[n][c0..c0+63] = act( sum_k X[n][k] * W[k][c] + bias[c] )
// thread = node (256-node tile); weights are block-uniform -> scalar loads.
// ---------------------------------------------------------------------------
__launch_bounds__(256, 3)
__global__ void gemm_cnode(const float* __restrict__ X,
                           const float* __restrict__ W,
                           const float* __restrict__ bias,
                           float* __restrict__ Y,
                           int N, int act)
{
    __shared__ float xs[256][36];            // 32 k-cols + pad
    const int tid = threadIdx.x;
    const int n0  = blockIdx.x * 256;
    const int c0  = blockIdx.y * 64;

    float acc[64];
    #pragma unroll
    for (int i = 0; i < 64; ++i) acc[i] = 0.f;

    for (int kt = 0; kt < 8; ++kt) {         // 8 k-tiles of 32
        __syncthreads();
        #pragma unroll
        for (int i = 0; i < 8; ++i) {
            int v  = i * 256 + tid;          // float4 index 0..2047
            int r  = v >> 3;                 // node row 0..255
            int c4 = (v & 7) << 2;           // k-col 0,4,..,28
            float4 u;
            if (n0 + r < N) {
                u = *reinterpret_cast<const float4*>(X + (size_t)(n0 + r) * IFZ + kt * 32 + c4);
            } else {
                u = make_float4(0.f, 0.f, 0.f, 0.f);
            }
            *reinterpret_cast<float4*>(&xs[r][c4]) = u;
        }
        __syncthreads();

        #pragma unroll 1
        for (int kk = 0; kk < 32; kk += 4) {
            float4 xv = *reinterpret_cast<const float4*>(&xs[tid][kk]);
            float xf[4] = { xv.x, xv.y, xv.z, xv.w };
            const float* wr = W + (size_t)(kt * 32 + kk) * HF + c0;
            #pragma unroll
            for (int j = 0; j < 4; ++j) {
                const float* w = wr + j * HF;
                #pragma unroll
                for (int cc = 0; cc < 64; ++cc)
                    acc[cc] = fmaf(xf[j], w[cc], acc[cc]);
            }
        }
    }

    if (n0 + tid < N) {
        float* yrow = Y + (size_t)(n0 + tid) * HF + c0;
        #pragma unroll
        for (int c4 = 0; c4 < 64; c4 += 4) {
            float4 u;
            float a[4];
            #pragma unroll
            for (int i = 0; i < 4; ++i) {
                a[i] = acc[c4 + i];
                if (bias) a[i] += bias[c0 + c4 + i];
                if (act == 1) a[i] = 1.f / (1.f + __expf(-a[i]));
            }
            u.x = a[0]; u.y = a[1]; u.z = a[2]; u.w = a[3];
            *reinterpret_cast<float4*>(yrow + c4) = u;
        }
    }
}

// ---------------------------------------------------------------------------
// Per-node attention: gather K/V, RoPE, LN(x2)@Wb bias, softmax, PV, gate
// one block (256 thr) per node
// ---------------------------------------------------------------------------
__launch_bounds__(256, 3)
__global__ void attn_node(const float* __restrict__ Qb,
                          const float* __restrict__ Kb,
                          const float* __restrict__ Vb,
                          const float* __restrict__ Gb,
                          const float* __restrict__ x2b,
                          const float* __restrict__ peb,
                          const int* __restrict__ eidx,
                          const float* __restrict__ blng,
                          const float* __restrict__ blnb,
                          const float* __restrict__ Wbb,
                          float* __restrict__ AOb,
                          int N)
{
    __shared__ float ks[KZ][260];
    __shared__ float vs[KZ][260];
    __shared__ float qs[256];
    __shared__ float csn[KZ][32];
    __shared__ float snn[KZ][32];
    __shared__ float csq[32], snq[32];
    __shared__ float bias2[KZ][8];
    __shared__ float sc[KZ][8];
    __shared__ float wn[KZ][8];
    __shared__ int   eix[KZ];

    const int n    = blockIdx.x;
    const int tid  = threadIdx.x;
    const int lane = tid & 63;
    const int wid  = tid >> 6;

    if (tid < KZ) eix[tid] = eidx[(size_t)n * KZ + tid];
    __syncthreads();

    // sin/cos tables: self (32) and 16 neighbors (16x32)
    if (tid < 32) {
        float a = peb[(size_t)n * AFZ + tid];
        float s, c; __sincosf(a, &s, &c); snq[tid] = s; csq[tid] = c;
    }
    #pragma unroll
    for (int p = 0; p < 2; ++p) {
        int e = p * 8 + (tid >> 5);
        int f = tid & 31;
        float a = peb[(size_t)eix[e] * AFZ + f];
        float s, c; __sincosf(a, &s, &c);
        snn[e][f] = s; csn[e][f] = c;
    }
    __syncthreads();

    // Q rope (partner element via xor-16 shuffle; tid^16 stays in-wave)
    {
        float qv = Qb[(size_t)n * HF + tid];
        float pv = __shfl_xor(qv, 16);
        int f = tid & 31;
        float sgn = (f < 16) ? -1.f : 1.f;
        qs[tid] = qv * csq[f] + sgn * pv * snq[f];
    }

    // K/V gather + K rope: one wave per neighbor row, 4 passes
    for (int r = 0; r < 4; ++r) {
        int e = r * 4 + wid;
        size_t rowO = (size_t)eix[e] * HF + lane * 4;
        float4 uk = *reinterpret_cast<const float4*>(Kb + rowO);
        float4 uv = *reinterpret_cast<const float4*>(Vb + rowO);
        float kv[4] = { uk.x, uk.y, uk.z, uk.w };
        float vv[4] = { uv.x, uv.y, uv.z, uv.w };
        float pv[4];
        #pragma unroll
        for (int i = 0; i < 4; ++i) pv[i] = __shfl_xor(kv[i], 4);  // j^16 -> lane^4
        #pragma unroll
        for (int i = 0; i < 4; ++i) {
            int j = lane * 4 + i;
            int f = j & 31;
            float sgn = (f < 16) ? -1.f : 1.f;
            ks[e][j] = kv[i] * csn[e][f] + sgn * pv[i] * snn[e][f];
            vs[e][j] = vv[i];
        }
    }

    // LN(x2 row) + fused bias2 = ln @ Wb : one wave per row, 4 passes
    for (int rr = 0; rr < 4; ++rr) {
        int row = rr * 4 + wid;
        const float* xr = x2b + ((size_t)n * KZ + row) * IFZ + lane * 4;
        float4 u = *reinterpret_cast<const float4*>(xr);
        float x[4] = { u.x, u.y, u.z, u.w };
        float s = x[0] + x[1] + x[2] + x[3];
        float q = x[0]*x[0] + x[1]*x[1] + x[2]*x[2] + x[3]*x[3];
        #pragma unroll
        for (int o = 32; o > 0; o >>= 1) { s += __shfl_xor(s, o); q += __shfl_xor(q, o); }
        float m    = s * (1.f / 256.f);
        float var  = q * (1.f / 256.f) - m * m;
        float rstd = rsqrtf(var + 1e-5f);
        float ph[8] = {0,0,0,0,0,0,0,0};
        #pragma unroll
        for (int i = 0; i < 4; ++i) {
            int f = lane * 4 + i;
            float lnv = (x[i] - m) * rstd * blng[f] + blnb[f];
            #pragma unroll
            for (int h = 0; h < 8; ++h)
                ph[h] = fmaf(lnv, Wbb[f * 8 + h], ph[h]);
        }
        #pragma unroll
        for (int h = 0; h < 8; ++h) {
            #pragma unroll
            for (int o = 32; o > 0; o >>= 1) ph[h] += __shfl_xor(ph[h], o);
        }
        #pragma unroll
        for (int h = 0; h < 8; ++h)
            if (lane == h) bias2[row][h] = ph[h];
    }
    __syncthreads();

    // scores[e][h] = q.k/sqrt(32) + bias2
    if (tid < 128) {
        int e = tid >> 3, h = tid & 7;
        float s = 0.f;
        #pragma unroll
        for (int f = 0; f < 32; ++f)
            s = fmaf(qs[h * 32 + f], ks[e][h * 32 + f], s);
        sc[e][h] = s * 0.17677669529663687f + bias2[e][h];
    }
    __syncthreads();

    // softmax over e (neighbors)
    if (tid < 8) {
        int h = tid;
        float m = -1e30f;
        #pragma unroll
        for (int e = 0; e < KZ; ++e) m = fmaxf(m, sc[e][h]);
        float ex[KZ], sum = 0.f;
        #pragma unroll
        for (int e = 0; e < KZ; ++e) { ex[e] = __expf(sc[e][h] - m); sum += ex[e]; }
        float inv = 1.f / sum;
        #pragma unroll
        for (int e = 0; e < KZ; ++e) wn[e][h] = ex[e] * inv;
    }
    __syncthreads();

    // out = gate * sum_e wn * v
    {
        int h = tid >> 5;
        float o = 0.f;
        #pragma unroll
        for (int e = 0; e < KZ; ++e) o = fmaf(wn[e][h], vs[e][tid], o);
        float g = Gb[(size_t)n * HF + tid];
        AOb[(size_t)n * HF + tid] = o * g;
    }
}

// ---------------------------------------------------------------------------
// final: LN( RAW + sqrt(2)*x1 ) -> out     (one wave per row)
// ---------------------------------------------------------------------------
__launch_bounds__(256, 8)
__global__ void final_ln(const float* __restrict__ RAWb,
                         const float* __restrict__ x1b,
                         const float* __restrict__ g1,
                         const float* __restrict__ b1,
                         float* __restrict__ outb,
                         int N)
{
    int n    = blockIdx.x * 4 + (threadIdx.x >> 6);
    int lane = threadIdx.x & 63;
    if (n >= N) return;
    const size_t off = (size_t)n * IFZ + lane * 4;
    float4 ur = *reinterpret_cast<const float4*>(RAWb + off);
    float4 ux = *reinterpret_cast<const float4*>(x1b + off);
    float x[4];
    x[0] = ur.x + 1.4142135623730951f * ux.x;
    x[1] = ur.y + 1.4142135623730951f * ux.y;
    x[2] = ur.z + 1.4142135623730951f * ux.z;
    x[3] = ur.w + 1.4142135623730951f * ux.w;
    float s = x[0] + x[1] + x[2] + x[3];
    float q = x[0]*x[0] + x[1]*x[1] + x[2]*x[2] + x[3]*x[3];
    #pragma unroll
    for (int o = 32; o > 0; o >>= 1) { s += __shfl_xor(s, o); q += __shfl_xor(q, o); }
    float m    = s * (1.f / 256.f);
    float var  = q * (1.f / 256.f) - m * m;
    float rstd = rsqrtf(var + 1e-5f);
    float4 uo;
    {
        int f = lane * 4;
        uo.x = (x[0] - m) * rstd * g1[f + 0] + b1[f + 0];
        uo.y = (x[1] - m) * rstd * g1[f + 1] + b1[f + 1];
        uo.z = (x[2] - m) * rstd * g1[f + 2] + b1[f + 2];
        uo.w = (x[3] - m) * rstd * g1[f + 3] + b1[f + 3];
    }
    *reinterpret_cast<float4*>(outb + off) = uo;
}

// ---------------------------------------------------------------------------
extern "C" void kernel_launch(void* const* d_in, const int* in_sizes, int n_in,
                              void* d_out, int out_size, void* d_ws, size_t ws_size,
                              hipStream_t stream)
{
    const float* x1   = (const float*)d_in[0];
    const float* x2   = (const float*)d_in[1];
    const float* pe   = (const float*)d_in[2];
    const int*   ei   = (const int*)d_in[3];
    const float* wq   = (const float*)d_in[4];
    const float* wk   = (const float*)d_in[5];
    const float* wv   = (const float*)d_in[6];
    const float* wb   = (const float*)d_in[7];
    const float* blng = (const float*)d_in[8];
    const float* blnb = (const float*)d_in[9];
    const float* wg   = (const float*)d_in[10];
    const float* bg   = (const float*)d_in[11];
    const float* wbk  = (const float*)d_in[12];
    const float* bbk  = (const float*)d_in[13];
    const float* g1   = (const float*)d_in[14];
    const float* b1   = (const float*)d_in[15];

    const int N = in_sizes[0] / IFZ;

    const size_t S = ((size_t)N * HF * sizeof(float) + 4095) & ~(size_t)4095;
    float* Qb = (float*)d_ws;
    float* Kb = (float*)((char*)d_ws + S);
    float* Vb = (float*)((char*)d_ws + 2 * S);
    float* Gb = (float*)((char*)d_ws + 3 * S);
    float* AOb  = Qb;   // reuse: block n reads Q[n] before writing AO[n]
    float* RAWb = Kb;   // reuse: attention finished before this is written

    const int nt = (N + 255) / 256;
    gemm_cnode<<<dim3(nt, 4), 256, 0, stream>>>(x1, wq, nullptr, Qb, N, 0);
    gemm_cnode<<<dim3(nt, 4), 256, 0, stream>>>(x1, wk, nullptr, Kb, N, 0);
    gemm_cnode<<<dim3(nt, 4), 256, 0, stream>>>(x1, wv, nullptr, Vb, N, 0);
    gemm_cnode<<<dim3(nt, 4), 256, 0, stream>>>(x1, wg, bg,      Gb, N, 1);

    attn_node<<<dim3(N), 256, 0, stream>>>(Qb, Kb, Vb, Gb, x2, pe, ei, blng, blnb, wb, AOb, N);

    gemm_cnode<<<dim3(nt, 4), 256, 0, stream>>>(AOb, wbk, bbk, RAWb, N, 0);

    final_ln<<<dim3((N + 3) / 4), 256, 0, stream>>>(RAWb, x1, g1, b1, (float*)d_out, N);
}

// Round 3
// 443.963 us; speedup vs baseline: 2.2992x; 2.2992x over previous
//
#include <hip/hip_runtime.h>
#include <math.h>

#define IFZ 256
#define KZ  16
#define AHZ 8
#define AFZ 32
#define HF  256   // AHZ*AFZ

typedef _Float16 half8 __attribute__((ext_vector_type(8)));
typedef _Float16 half4 __attribute__((ext_vector_type(4)));
typedef float    f32x4 __attribute__((ext_vector_type(4)));

#define FLAG_BIAS 1
#define FLAG_SIG  2
#define FLAG_ROPE 4
#define FLAG_F16  8

// ---------------------------------------------------------------------------
// f32 -> f16 vector convert (x1 -> x1h)
// ---------------------------------------------------------------------------
__global__ void conv_f16(const float* __restrict__ in, _Float16* __restrict__ out, int n4)
{
    int i = blockIdx.x * 256 + threadIdx.x;
    if (i >= n4) return;
    float4 v = reinterpret_cast<const float4*>(in)[i];
    half4 h;
    h[0] = (_Float16)v.x; h[1] = (_Float16)v.y;
    h[2] = (_Float16)v.z; h[3] = (_Float16)v.w;
    reinterpret_cast<half4*>(out)[i] = h;
}

// ---------------------------------------------------------------------------
// Weight transpose + convert: WT[m][c][k] = (f16) W_m[k][c]   (5 x 256x256)
// ---------------------------------------------------------------------------
__global__ void conv_wt(const float* __restrict__ w0, const float* __restrict__ w1,
                        const float* __restrict__ w2, const float* __restrict__ w3,
                        const float* __restrict__ w4, _Float16* __restrict__ out)
{
    int k = blockIdx.x;      // 0..255
    int m = blockIdx.y;      // 0..4
    int c = threadIdx.x;     // 0..255
    const float* w = (m == 0) ? w0 : (m == 1) ? w1 : (m == 2) ? w2 : (m == 3) ? w3 : w4;
    out[(size_t)m * 65536 + (size_t)c * 256 + k] = (_Float16)w[(size_t)k * 256 + c];
}

// ---------------------------------------------------------------------------
// MFMA GEMM: out[n][c] = epilogue( sum_k A[n][k] * W[k][c] )
// A: f16 [N][256] row-major. BT: f16 [256 cols][256 k] (W transposed).
// tile 64x64, 4 waves, mfma_f32_16x16x32_f16.
// epilogue: optional bias, sigmoid, RoPE (pairs c, c^16 within 32-block), f16/f32 out
// ---------------------------------------------------------------------------
__launch_bounds__(256)
__global__ void gemm16(const _Float16* __restrict__ A, const _Float16* __restrict__ BT,
                       const float* __restrict__ bias, const float* __restrict__ pe,
                       void* __restrict__ out, int N, int flags)
{
    __shared__ _Float16 as[64][40];   // 64 rows x 32 k (+8 pad)
    __shared__ _Float16 bs[64][40];   // 64 cols x 32 k (+8 pad)

    const int tid = threadIdx.x;
    const int l   = tid & 63;
    const int w   = tid >> 6;
    const int n0  = blockIdx.x * 64;
    const int c0  = blockIdx.y * 64;

    f32x4 acc[4];
    #pragma unroll
    for (int b = 0; b < 4; ++b) { acc[b][0]=0.f; acc[b][1]=0.f; acc[b][2]=0.f; acc[b][3]=0.f; }

    const int srow = tid >> 2;         // 0..63
    const int sch  = (tid & 3) * 8;    // 0,8,16,24

    for (int kt = 0; kt < 8; ++kt) {
        const int k0 = kt * 32;
        half8 av{};
        if (n0 + srow < N)
            av = *reinterpret_cast<const half8*>(A + (size_t)(n0 + srow) * IFZ + k0 + sch);
        half8 bv = *reinterpret_cast<const half8*>(BT + (size_t)(c0 + srow) * IFZ + k0 + sch);
        __syncthreads();   // protect previous iteration's reads
        *reinterpret_cast<half8*>(&as[srow][sch]) = av;
        *reinterpret_cast<half8*>(&bs[srow][sch]) = bv;
        __syncthreads();

        half8 af = *reinterpret_cast<const half8*>(&as[16 * w + (l & 15)][8 * (l >> 4)]);
        #pragma unroll
        for (int b = 0; b < 4; ++b) {
            half8 bf = *reinterpret_cast<const half8*>(&bs[16 * b + (l & 15)][8 * (l >> 4)]);
            acc[b] = __builtin_amdgcn_mfma_f32_16x16x32_f16(af, bf, acc[b], 0, 0, 0);
        }
    }

    // C/D layout: col = c0 + 16b + (l&15), row = n0 + 16w + 4*(l>>4) + r
    #pragma unroll
    for (int r = 0; r < 4; ++r) {
        const int grow = n0 + 16 * w + ((l >> 4) << 2) + r;
        if (grow >= N) continue;
        if (flags & FLAG_ROPE) {
            #pragma unroll
            for (int pb = 0; pb < 4; pb += 2) {
                float a0 = pe[(size_t)grow * AFZ + (l & 15)];
                float a1 = pe[(size_t)grow * AFZ + 16 + (l & 15)];
                float s0, c0f, s1, c1f;
                __sincosf(a0, &s0, &c0f);
                __sincosf(a1, &s1, &c1f);
                float v0 = acc[pb][r], v1 = acc[pb + 1][r];
                float o0 = v0 * c0f - v1 * s0;   // f < 16: k[f]cos - k[f+16]sin
                float o1 = v1 * c1f + v0 * s1;   // f >=16: k[f]cos + k[f-16]sin
                _Float16* o = (_Float16*)out;
                o[(size_t)grow * HF + c0 + 16 * pb       + (l & 15)] = (_Float16)o0;
                o[(size_t)grow * HF + c0 + 16 * (pb + 1) + (l & 15)] = (_Float16)o1;
            }
        } else {
            #pragma unroll
            for (int b = 0; b < 4; ++b) {
                float v = acc[b][r];
                const int c = c0 + 16 * b + (l & 15);
                if (flags & FLAG_BIAS) v += bias[c];
                if (flags & FLAG_SIG)  v = 1.f / (1.f + __expf(-v));
                if (flags & FLAG_F16)  ((_Float16*)out)[(size_t)grow * HF + c] = (_Float16)v;
                else                   ((float*)out)[(size_t)grow * HF + c] = v;
            }
        }
    }
}

// ---------------------------------------------------------------------------
// bias2[row][h] = LN(x2[row]) @ Wb   (row = n*KZ+e), one wave per row
// ---------------------------------------------------------------------------
__launch_bounds__(256)
__global__ void bias2_kern(const float* __restrict__ x2, const float* __restrict__ g,
                           const float* __restrict__ b, const float* __restrict__ Wb,
                           float* __restrict__ out, int R)
{
    const int row = blockIdx.x * 4 + (threadIdx.x >> 6);
    const int l   = threadIdx.x & 63;
    if (row >= R) return;

    float4 xv = *reinterpret_cast<const float4*>(x2 + (size_t)row * IFZ + 4 * l);
    float x[4] = { xv.x, xv.y, xv.z, xv.w };
    float s  = x[0] + x[1] + x[2] + x[3];
    float qq = x[0]*x[0] + x[1]*x[1] + x[2]*x[2] + x[3]*x[3];
    #pragma unroll
    for (int o = 32; o > 0; o >>= 1) { s += __shfl_xor(s, o); qq += __shfl_xor(qq, o); }
    float m    = s * (1.f / 256.f);
    float var  = qq * (1.f / 256.f) - m * m;
    float rstd = rsqrtf(var + 1e-5f);

    float4 gv = *reinterpret_cast<const float4*>(g + 4 * l);
    float4 bv = *reinterpret_cast<const float4*>(b + 4 * l);
    float lnv[4];
    lnv[0] = (x[0] - m) * rstd * gv.x + bv.x;
    lnv[1] = (x[1] - m) * rstd * gv.y + bv.y;
    lnv[2] = (x[2] - m) * rstd * gv.z + bv.z;
    lnv[3] = (x[3] - m) * rstd * gv.w + bv.w;

    float ph[8] = {0,0,0,0,0,0,0,0};
    #pragma unroll
    for (int i = 0; i < 4; ++i) {
        const int f = 4 * l + i;
        float4 w0 = *reinterpret_cast<const float4*>(Wb + (size_t)f * 8);
        float4 w1 = *reinterpret_cast<const float4*>(Wb + (size_t)f * 8 + 4);
        ph[0] = fmaf(lnv[i], w0.x, ph[0]); ph[1] = fmaf(lnv[i], w0.y, ph[1]);
        ph[2] = fmaf(lnv[i], w0.z, ph[2]); ph[3] = fmaf(lnv[i], w0.w, ph[3]);
        ph[4] = fmaf(lnv[i], w1.x, ph[4]); ph[5] = fmaf(lnv[i], w1.y, ph[5]);
        ph[6] = fmaf(lnv[i], w1.z, ph[6]); ph[7] = fmaf(lnv[i], w1.w, ph[7]);
    }
    #pragma unroll
    for (int h = 0; h < 8; ++h) {
        #pragma unroll
        for (int o = 32; o > 0; o >>= 1) ph[h] += __shfl_xor(ph[h], o);
    }
    if (l == 0) {
        float4 o0 = { ph[0], ph[1], ph[2], ph[3] };
        float4 o1 = { ph[4], ph[5], ph[6], ph[7] };
        *reinterpret_cast<float4*>(out + (size_t)row * 8)     = o0;
        *reinterpret_cast<float4*>(out + (size_t)row * 8 + 4) = o1;
    }
}

// ---------------------------------------------------------------------------
// Slim attention: gather roped-K/V (f16), scores + bias2, softmax, PV, gate
// one block per node; wave w owns neighbors 4w..4w+3 in registers
// ---------------------------------------------------------------------------
__launch_bounds__(256)
__global__ void attn_node(const _Float16* __restrict__ Qh, const _Float16* __restrict__ Kh,
                          const _Float16* __restrict__ Vh, const _Float16* __restrict__ Gh,
                          const int* __restrict__ eidx, const float* __restrict__ b2,
                          _Float16* __restrict__ AOh, int N)
{
    __shared__ float sc[KZ][9];
    __shared__ float wn[KZ][9];
    __shared__ float po[4][264];
    __shared__ int   eix[KZ];

    const int n   = blockIdx.x;
    const int tid = threadIdx.x;
    const int l   = tid & 63;
    const int w   = tid >> 6;

    if (tid < KZ) eix[tid] = eidx[(size_t)n * KZ + tid];
    __syncthreads();

    float q[4];
    {
        half4 qh = *reinterpret_cast<const half4*>(Qh + (size_t)n * HF + 4 * l);
        q[0] = (float)qh[0]; q[1] = (float)qh[1]; q[2] = (float)qh[2]; q[3] = (float)qh[3];
    }

    float kv[4][4], vv[4][4];
    #pragma unroll
    for (int e4 = 0; e4 < 4; ++e4) {
        const int row = eix[w * 4 + e4];
        half4 kh = *reinterpret_cast<const half4*>(Kh + (size_t)row * HF + 4 * l);
        half4 vh = *reinterpret_cast<const half4*>(Vh + (size_t)row * HF + 4 * l);
        #pragma unroll
        for (int i = 0; i < 4; ++i) { kv[e4][i] = (float)kh[i]; vv[e4][i] = (float)vh[i]; }
    }

    // scores: lane holds elems 4l..4l+3 (head h = l>>3); reduce over 8-lane head group
    #pragma unroll
    for (int e4 = 0; e4 < 4; ++e4) {
        float s = q[0]*kv[e4][0] + q[1]*kv[e4][1] + q[2]*kv[e4][2] + q[3]*kv[e4][3];
        s += __shfl_xor(s, 1); s += __shfl_xor(s, 2); s += __shfl_xor(s, 4);
        if ((l & 7) == 0) sc[w * 4 + e4][l >> 3] = s * 0.17677669529663687f;
    }
    __syncthreads();

    // softmax over e per head: 128 threads, (e,h) grid, 16-lane group reduce
    if (tid < 128) {
        const int e = l & 15;
        const int h = ((tid >> 6) << 2) + (l >> 4);
        float v = sc[e][h] + b2[((size_t)n * KZ + e) * AHZ + h];
        float m = v;
        m = fmaxf(m, __shfl_xor(m, 1)); m = fmaxf(m, __shfl_xor(m, 2));
        m = fmaxf(m, __shfl_xor(m, 4)); m = fmaxf(m, __shfl_xor(m, 8));
        float ex = __expf(v - m);
        float sum = ex;
        sum += __shfl_xor(sum, 1); sum += __shfl_xor(sum, 2);
        sum += __shfl_xor(sum, 4); sum += __shfl_xor(sum, 8);
        wn[e][h] = ex / sum;
    }
    __syncthreads();

    // PV partials per wave
    {
        const int h = l >> 3;
        float o[4] = {0.f, 0.f, 0.f, 0.f};
        #pragma unroll
        for (int e4 = 0; e4 < 4; ++e4) {
            const float we = wn[w * 4 + e4][h];
            #pragma unroll
            for (int i = 0; i < 4; ++i) o[i] = fmaf(we, vv[e4][i], o[i]);
        }
        float4 of = { o[0], o[1], o[2], o[3] };
        *reinterpret_cast<float4*>(&po[w][4 * l]) = of;
    }
    __syncthreads();

    // combine + gate + store f16
    if (tid < 64) {
        float4 r0 = *reinterpret_cast<const float4*>(&po[0][4 * l]);
        float4 r1 = *reinterpret_cast<const float4*>(&po[1][4 * l]);
        float4 r2 = *reinterpret_cast<const float4*>(&po[2][4 * l]);
        float4 r3 = *reinterpret_cast<const float4*>(&po[3][4 * l]);
        half4 gh = *reinterpret_cast<const half4*>(Gh + (size_t)n * HF + 4 * l);
        half4 oh;
        oh[0] = (_Float16)((r0.x + r1.x + r2.x + r3.x) * (float)gh[0]);
        oh[1] = (_Float16)((r0.y + r1.y + r2.y + r3.y) * (float)gh[1]);
        oh[2] = (_Float16)((r0.z + r1.z + r2.z + r3.z) * (float)gh[2]);
        oh[3] = (_Float16)((r0.w + r1.w + r2.w + r3.w) * (float)gh[3]);
        *reinterpret_cast<half4*>(AOh + (size_t)n * HF + 4 * l) = oh;
    }
}

// ---------------------------------------------------------------------------
// final: LN( RAW + sqrt(2)*x1 ) -> out     (one wave per row)
// ---------------------------------------------------------------------------
__launch_bounds__(256)
__global__ void final_ln(const float* __restrict__ RAWb,
                         const float* __restrict__ x1b,
                         const float* __restrict__ g1,
                         const float* __restrict__ b1,
                         float* __restrict__ outb,
                         int N)
{
    int n    = blockIdx.x * 4 + (threadIdx.x >> 6);
    int lane = threadIdx.x & 63;
    if (n >= N) return;
    const size_t off = (size_t)n * IFZ + lane * 4;
    float4 ur = *reinterpret_cast<const float4*>(RAWb + off);
    float4 ux = *reinterpret_cast<const float4*>(x1b + off);
    float x[4];
    x[0] = ur.x + 1.4142135623730951f * ux.x;
    x[1] = ur.y + 1.4142135623730951f * ux.y;
    x[2] = ur.z + 1.4142135623730951f * ux.z;
    x[3] = ur.w + 1.4142135623730951f * ux.w;
    float s = x[0] + x[1] + x[2] + x[3];
    float q = x[0]*x[0] + x[1]*x[1] + x[2]*x[2] + x[3]*x[3];
    #pragma unroll
    for (int o = 32; o > 0; o >>= 1) { s += __shfl_xor(s, o); q += __shfl_xor(q, o); }
    float m    = s * (1.f / 256.f);
    float var  = q * (1.f / 256.f) - m * m;
    float rstd = rsqrtf(var + 1e-5f);
    float4 uo;
    {
        int f = lane * 4;
        uo.x = (x[0] - m) * rstd * g1[f + 0] + b1[f + 0];
        uo.y = (x[1] - m) * rstd * g1[f + 1] + b1[f + 1];
        uo.z = (x[2] - m) * rstd * g1[f + 2] + b1[f + 2];
        uo.w = (x[3] - m) * rstd * g1[f + 3] + b1[f + 3];
    }
    *reinterpret_cast<float4*>(outb + off) = uo;
}

// ---------------------------------------------------------------------------
extern "C" void kernel_launch(void* const* d_in, const int* in_sizes, int n_in,
                              void* d_out, int out_size, void* d_ws, size_t ws_size,
                              hipStream_t stream)
{
    const float* x1   = (const float*)d_in[0];
    const float* x2   = (const float*)d_in[1];
    const float* pe   = (const float*)d_in[2];
    const int*   ei   = (const int*)d_in[3];
    const float* wq   = (const float*)d_in[4];
    const float* wk   = (const float*)d_in[5];
    const float* wv   = (const float*)d_in[6];
    const float* wb   = (const float*)d_in[7];
    const float* blng = (const float*)d_in[8];
    const float* blnb = (const float*)d_in[9];
    const float* wg   = (const float*)d_in[10];
    const float* bg   = (const float*)d_in[11];
    const float* wbk  = (const float*)d_in[12];
    const float* bbk  = (const float*)d_in[13];
    const float* g1   = (const float*)d_in[14];
    const float* b1   = (const float*)d_in[15];

    const int N = in_sizes[0] / IFZ;

    const size_t S2 = (((size_t)N * HF * 2) + 4095) & ~(size_t)4095;   // f16 buffer size
    char* base = (char*)d_ws;
    _Float16* X1H = (_Float16*)(base);
    _Float16* QH  = (_Float16*)(base + 1 * S2);
    _Float16* KH  = (_Float16*)(base + 2 * S2);
    _Float16* VH  = (_Float16*)(base + 3 * S2);
    _Float16* GH  = (_Float16*)(base + 4 * S2);
    float*    B2  = (float*)   (base + 5 * S2);     // N*KZ*8 f32 == S2 bytes
    _Float16* WT  = (_Float16*)(base + 6 * S2);     // 5 x 65536 f16
    _Float16* AOH = QH;                              // reuse: block n reads Q[n] then writes AO[n]
    float*    RAW = (float*)(base + 2 * S2);         // reuse KH+VH region (f32, 2*S2 bytes)

    // conversions
    conv_f16<<<dim3((N * IFZ / 4 + 255) / 256), 256, 0, stream>>>(x1, X1H, N * IFZ / 4);
    conv_wt<<<dim3(256, 5), 256, 0, stream>>>(wq, wk, wv, wg, wbk, WT);

    const int nt = (N + 63) / 64;
    // Q,K: rope'd f16; V: plain f16; G: sigmoid(x@Wg+bg) f16
    gemm16<<<dim3(nt, 4), 256, 0, stream>>>(X1H, WT,           nullptr, pe, QH, N, FLAG_ROPE | FLAG_F16);
    gemm16<<<dim3(nt, 4), 256, 0, stream>>>(X1H, WT + 65536,   nullptr, pe, KH, N, FLAG_ROPE | FLAG_F16);
    gemm16<<<dim3(nt, 4), 256, 0, stream>>>(X1H, WT + 131072,  nullptr, nullptr, VH, N, FLAG_F16);
    gemm16<<<dim3(nt, 4), 256, 0, stream>>>(X1H, WT + 196608,  bg,      nullptr, GH, N, FLAG_BIAS | FLAG_SIG | FLAG_F16);

    bias2_kern<<<dim3((N * KZ + 3) / 4), 256, 0, stream>>>(x2, blng, blnb, wb, B2, N * KZ);

    attn_node<<<dim3(N), 256, 0, stream>>>(QH, KH, VH, GH, ei, B2, AOH, N);

    gemm16<<<dim3(nt, 4), 256, 0, stream>>>(AOH, WT + 262144, bbk, nullptr, RAW, N, FLAG_BIAS);

    final_ln<<<dim3((N + 3) / 4), 256, 0, stream>>>(RAW, x1, g1, b1, (float*)d_out, N);
}